// Round 2
// baseline (9776.861 us; speedup 1.0000x reference)
//
#include <hip/hip_runtime.h>
#include <hip/hip_bf16.h>
#include <cstdint>
#include <cstddef>

typedef unsigned short u16;
typedef __attribute__((ext_vector_type(8))) __bf16 bf16x8;
typedef __attribute__((ext_vector_type(4))) float f32x4;

#define B_   128
#define T_   256
#define E_   512
#define H_   1024
#define G4_  4096
#define F_   512
#define O_   10
#define NBLK 128
#define WROW 1544   // LDS row stride in elems (1536 + 8 pad -> conflict-free ds_read_b128)

__device__ __forceinline__ u16 f2bf(float f) {
  unsigned int u = __float_as_uint(f);
  u += 0x7FFFu + ((u >> 16) & 1u);
  return (u16)(u >> 16);
}
__device__ __forceinline__ float bf2f(u16 h) {
  return __uint_as_float(((unsigned int)h) << 16);
}
__device__ __forceinline__ float fsigmoid(float x) {
  return 1.f / (1.f + __expf(-x));
}
__device__ __forceinline__ float ftanh(float x) {
  float ax = fabsf(x);
  float t = __expf(-2.f * ax);
  float r = (1.f - t) / (1.f + t);
  return copysignf(r, x);
}

// ---------------------------------------------------------------- build xe16
// xe16[t*B+b][e] = bf16(emb[x[b][t]][e])   (contiguous per-step slice)
__global__ void build_xe(const int* __restrict__ x, const float* __restrict__ emb,
                         u16* __restrict__ xe16) {
  int id = blockIdx.x * 256 + threadIdx.x;   // over 32768*128 float4-groups
  int row = id >> 7;                          // b*T + t
  int c = (id & 127) << 2;
  int v = x[row];
  int b = row >> 8;                           // T_ = 256
  int t = row & 255;
  const float4 f = *(const float4*)&emb[(size_t)v * E_ + c];
  ushort4 o;
  o.x = f2bf(f.x); o.y = f2bf(f.y); o.z = f2bf(f.z); o.w = f2bf(f.w);
  *(ushort4*)&xe16[((size_t)(t * B_ + b)) * E_ + c] = o;
}

// ---------------------------------------------------------------- topic bias
// tb[m][g] = b[g] + sum_k x_top[m][k] * w_th[g][k]   (fp32, time-invariant)
__global__ void topicb(const float* __restrict__ x_top, const float* __restrict__ w_th,
                       const float* __restrict__ bias, float* __restrict__ tb) {
  int m = blockIdx.x;
  __shared__ float xt[128];
  if (threadIdx.x < 128) xt[threadIdx.x] = x_top[m * 128 + threadIdx.x];
  __syncthreads();
  for (int g = threadIdx.x; g < G4_; g += 256) {
    const float* wr = &w_th[(size_t)g * 128];
    float s = bias[g];
#pragma unroll 8
    for (int k = 0; k < 128; ++k) s += xt[k] * wr[k];
    tb[(size_t)m * G4_ + g] = s;
  }
}

// ---------------------------------------------------------------- grid barrier
__device__ __forceinline__ void gridbar(unsigned* cnt, unsigned target) {
  __syncthreads();      // all waves' stores drained to L2 (vmcnt before s_barrier)
  __threadfence();      // agent-scope release: write back local XCD L2
  if (threadIdx.x == 0) {
    __hip_atomic_fetch_add(cnt, 1u, __ATOMIC_RELEASE, __HIP_MEMORY_SCOPE_AGENT);
    while (__hip_atomic_load(cnt, __ATOMIC_ACQUIRE, __HIP_MEMORY_SCOPE_AGENT) < target)
      __builtin_amdgcn_s_sleep(1);
  }
  __syncthreads();
  __threadfence();      // agent-scope acquire: invalidate stale L1/L2 lines
}

// ---------------------------------------------------------------- persistent LSTM
// 128 blocks x 256 threads (cooperative). Block j owns h-cols [8j, 8j+8)
// = 32 gate cols, weight slice [32][1536] bf16 resident in LDS for all 256
// steps. Wave w covers m-rows [32w, 32w+32) (acc[2][2]). cx in registers.
__global__ __launch_bounds__(256) void lstm_persist(
    const u16* __restrict__ xe, u16* __restrict__ h0, u16* __restrict__ h1,
    const float* __restrict__ wih, const float* __restrict__ whh,
    const float* __restrict__ tb, unsigned* __restrict__ cnt) {
  __shared__ u16 Wl[32 * WROW];   // 98,816 B
  const int j = blockIdx.x;
  const int tid = threadIdx.x;

  // ---- stage weight slice to LDS (fp32 -> bf16), rows: [i(8) f(8) g(8) o(8)]
  for (int idx = tid; idx < 32 * 384; idx += 256) {
    int lc = idx / 384;
    int c = (idx - lc * 384) * 4;
    int g = (lc >> 3) * H_ + j * 8 + (lc & 7);
    float4 f;
    if (c < E_) f = *(const float4*)&wih[(size_t)g * E_ + c];
    else        f = *(const float4*)&whh[(size_t)g * H_ + (c - E_)];
    ushort4 o;
    o.x = f2bf(f.x); o.y = f2bf(f.y); o.z = f2bf(f.z); o.w = f2bf(f.w);
    *(ushort4*)&Wl[lc * WROW + c] = o;
  }
  __syncthreads();

  const int w = tid >> 6, l = tid & 63, r = l & 15, q = l >> 4;
  const int g0 = (r >> 3) * H_ + j * 8 + (r & 7);   // gates i/f
  const int g1 = g0 + 2 * H_;                        // gates g/o
  const int hcg = j * 8 + (r & 7);
  const bool lower = (r & 8) == 0;

  // ---- preload time-invariant bias (tb) into registers
  float tbr[2][2][4];
#pragma unroll
  for (int mi = 0; mi < 2; ++mi)
#pragma unroll
    for (int rr = 0; rr < 4; ++rr) {
      int m = w * 32 + mi * 16 + q * 4 + rr;
      tbr[mi][0][rr] = tb[(size_t)m * G4_ + g0];
      tbr[mi][1][rr] = tb[(size_t)m * G4_ + g1];
    }

  const u16* lb0 = &Wl[r * WROW];
  const u16* lb1 = &Wl[(16 + r) * WROW];

  float cxr[2][4] = {};   // cell state lives in registers (both lane halves
                          // compute identical values -> both stay correct)

  for (int t = 0; t < T_; ++t) {
    const u16* hin  = (t & 1) ? h1 : h0;
    u16*       hout = (t & 1) ? h0 : h1;
    f32x4 acc[2][2] = {};

    // K part 1: xe_t (k = 0..511), contiguous [t][B][E] slice
    const u16* pa0 = xe + ((size_t)(t * B_) + w * 32 + r) * E_ + q * 8;
    const u16* pa1 = pa0 + 16 * E_;
    int kc = q * 8;
#pragma unroll 4
    for (int it = 0; it < 16; ++it) {
      bf16x8 a0 = *(const bf16x8*)pa0; pa0 += 32;
      bf16x8 a1 = *(const bf16x8*)pa1; pa1 += 32;
      bf16x8 b0 = *(const bf16x8*)&lb0[kc];
      bf16x8 b1 = *(const bf16x8*)&lb1[kc];
      kc += 32;
      acc[0][0] = __builtin_amdgcn_mfma_f32_16x16x32_bf16(a0, b0, acc[0][0], 0, 0, 0);
      acc[0][1] = __builtin_amdgcn_mfma_f32_16x16x32_bf16(a0, b1, acc[0][1], 0, 0, 0);
      acc[1][0] = __builtin_amdgcn_mfma_f32_16x16x32_bf16(a1, b0, acc[1][0], 0, 0, 0);
      acc[1][1] = __builtin_amdgcn_mfma_f32_16x16x32_bf16(a1, b1, acc[1][1], 0, 0, 0);
    }
    // K part 2: hx (k = 512..1535)
    const u16* ph0 = hin + ((size_t)(w * 32 + r)) * H_ + q * 8;
    const u16* ph1 = ph0 + 16 * H_;
#pragma unroll 4
    for (int it = 0; it < 32; ++it) {
      bf16x8 a0 = *(const bf16x8*)ph0; ph0 += 32;
      bf16x8 a1 = *(const bf16x8*)ph1; ph1 += 32;
      bf16x8 b0 = *(const bf16x8*)&lb0[kc];
      bf16x8 b1 = *(const bf16x8*)&lb1[kc];
      kc += 32;
      acc[0][0] = __builtin_amdgcn_mfma_f32_16x16x32_bf16(a0, b0, acc[0][0], 0, 0, 0);
      acc[0][1] = __builtin_amdgcn_mfma_f32_16x16x32_bf16(a0, b1, acc[0][1], 0, 0, 0);
      acc[1][0] = __builtin_amdgcn_mfma_f32_16x16x32_bf16(a1, b0, acc[1][0], 0, 0, 0);
      acc[1][1] = __builtin_amdgcn_mfma_f32_16x16x32_bf16(a1, b1, acc[1][1], 0, 0, 0);
    }

    // epilogue: D col = lane&15 (gate col), row = q*4 + rr
#pragma unroll
    for (int mi = 0; mi < 2; ++mi)
#pragma unroll
      for (int rr = 0; rr < 4; ++rr) {
        int m = w * 32 + mi * 16 + q * 4 + rr;
        float v0 = acc[mi][0][rr] + tbr[mi][0][rr];
        float v1 = acc[mi][1][rr] + tbr[mi][1][rr];
        float p0 = __shfl_xor(v0, 8);
        float p1 = __shfl_xor(v1, 8);
        float iv = lower ? v0 : p0;
        float fv = lower ? p0 : v0;
        float gv = lower ? v1 : p1;
        float ov = lower ? p1 : v1;
        iv = fsigmoid(iv);
        fv = fsigmoid(fv);
        ov = fsigmoid(ov);
        gv = ftanh(gv);
        float cn = fv * cxr[mi][rr] + iv * gv;
        cxr[mi][rr] = cn;
        float hn = ov * ftanh(cn);
        if (lower) hout[(size_t)m * H_ + hcg] = f2bf(hn);
      }
    gridbar(cnt, (unsigned)(t + 1) * NBLK);
  }
}

// ---------------------------------------------------------------- fc1 + BN
__global__ void fc1_bn(const u16* __restrict__ hxf, const float* __restrict__ w,
                       const float* __restrict__ bvec, const float* __restrict__ gamma,
                       const float* __restrict__ beta, float* __restrict__ h1n) {
  const int f = blockIdx.x;
  const int m = threadIdx.x;
  __shared__ float wrow[H_];
  __shared__ float red[128];
  for (int k = m; k < H_; k += 128) wrow[k] = w[(size_t)f * H_ + k];
  __syncthreads();
  float s = bvec[f];
  const u16* hr = &hxf[(size_t)m * H_];
  for (int k = 0; k < H_; k += 4) {
    ushort4 h4 = *(const ushort4*)&hr[k];
    s += bf2f(h4.x) * wrow[k] + bf2f(h4.y) * wrow[k + 1] +
         bf2f(h4.z) * wrow[k + 2] + bf2f(h4.w) * wrow[k + 3];
  }
  red[m] = s;
  __syncthreads();
  for (int off = 64; off > 0; off >>= 1) {
    if (m < off) red[m] += red[m + off];
    __syncthreads();
  }
  float mu = red[0] * (1.f / 128.f);
  __syncthreads();
  float d = s - mu;
  red[m] = d * d;
  __syncthreads();
  for (int off = 64; off > 0; off >>= 1) {
    if (m < off) red[m] += red[m + off];
    __syncthreads();
  }
  float var = red[0] * (1.f / 128.f);
  h1n[(size_t)m * F_ + f] = d * rsqrtf(var + 1e-5f) * gamma[f] + beta[f];
}

// ---------------------------------------------------------------- fc2
__global__ void fc2k(const float* __restrict__ h1n, const float* __restrict__ w,
                     const float* __restrict__ bvec, float* __restrict__ out) {
  int id = blockIdx.x * 256 + threadIdx.x;   // 1280 total
  if (id >= B_ * O_) return;
  int m = id / O_;
  int o = id - m * O_;
  float s = bvec[o];
  const float* hr = &h1n[(size_t)m * F_];
  const float* wr = &w[(size_t)o * F_];
#pragma unroll 8
  for (int k = 0; k < F_; ++k) s += hr[k] * wr[k];
  out[(size_t)m * O_ + o] = s;
}

// ---------------------------------------------------------------- launch
extern "C" void kernel_launch(void* const* d_in, const int* in_sizes, int n_in,
                              void* d_out, int out_size, void* d_ws, size_t ws_size,
                              hipStream_t stream) {
  const int*   x     = (const int*)  d_in[0];
  const float* x_top = (const float*)d_in[1];
  const float* emb   = (const float*)d_in[2];
  const float* w_ih  = (const float*)d_in[3];
  const float* w_hh  = (const float*)d_in[4];
  const float* w_th  = (const float*)d_in[5];
  const float* bvec  = (const float*)d_in[6];
  const float* fc1_w = (const float*)d_in[7];
  const float* fc1_b = (const float*)d_in[8];
  const float* gamma = (const float*)d_in[9];
  const float* beta  = (const float*)d_in[10];
  const float* fc2_w = (const float*)d_in[11];
  const float* fc2_b = (const float*)d_in[12];
  float* out = (float*)d_out;

  // ws layout (bytes)
  const size_t OFF_XE  = 0;           // 33,554,432  xe16 [T][B][E] bf16
  const size_t OFF_TB  = 33554432;    //  2,097,152  tb   [B][4H] f32
  const size_t OFF_HX0 = 35651584;    //    262,144  hx ping bf16
  const size_t OFF_HX1 = 35913728;    //    262,144  hx pong bf16
  const size_t OFF_CNT = 36175872;    //      4,096  barrier counter
  const size_t OFF_H1  = 36179968;    //    262,144  h1n [B][F] f32
  const size_t NEED    = 36442112;
  if (!d_ws || ws_size < NEED) return;

  char* ws = (char*)d_ws;
  u16*      xe16 = (u16*)(ws + OFF_XE);
  float*    tb   = (float*)(ws + OFF_TB);
  u16*      hx0  = (u16*)(ws + OFF_HX0);
  u16*      hx1  = (u16*)(ws + OFF_HX1);
  unsigned* cnt  = (unsigned*)(ws + OFF_CNT);
  float*    h1n  = (float*)(ws + OFF_H1);

  // zero hx0, hx1, barrier counter (contiguous)
  hipMemsetAsync(ws + OFF_HX0, 0, 262144 * 2 + 4096, stream);

  build_xe<<<16384, 256, 0, stream>>>(x, emb, xe16);
  topicb<<<128, 256, 0, stream>>>(x_top, w_th, bvec, tb);

  {
    const u16* a0 = xe16;
    u16* a1 = hx0; u16* a2 = hx1;
    const float* a3 = w_ih; const float* a4 = w_hh; const float* a5 = tb;
    unsigned* a6 = cnt;
    void* args[] = { (void*)&a0, (void*)&a1, (void*)&a2, (void*)&a3,
                     (void*)&a4, (void*)&a5, (void*)&a6 };
    hipError_t e = hipLaunchCooperativeKernel((void*)lstm_persist, dim3(NBLK),
                                              dim3(256), args, 0, stream);
    if (e != hipSuccess) {
      // fallback: plain launch (128 blocks <= 256 CUs -> co-resident)
      lstm_persist<<<NBLK, 256, 0, stream>>>(xe16, hx0, hx1, w_ih, w_hh, tb, cnt);
    }
  }
  // T_=256 even -> final hx in hx0

  fc1_bn<<<F_, 128, 0, stream>>>(hx0, fc1_w, fc1_b, gamma, beta, h1n);
  fc2k<<<5, 256, 0, stream>>>(h1n, fc2_w, fc2_b, out);
}

// Round 3
// 3825.304 us; speedup vs baseline: 2.5558x; 2.5558x over previous
//
#include <hip/hip_runtime.h>
#include <hip/hip_bf16.h>
#include <cstdint>
#include <cstddef>

typedef unsigned short u16;
typedef __attribute__((ext_vector_type(8))) __bf16 bf16x8;
typedef __attribute__((ext_vector_type(4))) float f32x4;

#define B_   128
#define T_   256
#define E_   512
#define H_   1024
#define G4_  4096
#define F_   512
#define O_   10
#define NBLK 128

__device__ __forceinline__ u16 f2bf(float f) {
  unsigned int u = __float_as_uint(f);
  u += 0x7FFFu + ((u >> 16) & 1u);
  return (u16)(u >> 16);
}
__device__ __forceinline__ float bf2f(u16 h) {
  return __uint_as_float(((unsigned int)h) << 16);
}
__device__ __forceinline__ float fsigmoid(float x) {
  return 1.f / (1.f + __expf(-x));
}
__device__ __forceinline__ float ftanh(float x) {
  float ax = fabsf(x);
  float t = __expf(-2.f * ax);
  float r = (1.f - t) / (1.f + t);
  return copysignf(r, x);
}

// async global->LDS, 16B per lane; lds dest wave-uniform base + lane*16
__device__ __forceinline__ void glds16(const void* g, void* l) {
  __builtin_amdgcn_global_load_lds(
      (const __attribute__((address_space(1))) unsigned int*)g,
      (__attribute__((address_space(3))) unsigned int*)l, 16, 0, 0);
}

// ---------------------------------------------------------------- build xe16
// xe16[t*B+b][e] = bf16(emb[x[b][t]][e])   (contiguous per-step slice)
__global__ void build_xe(const int* __restrict__ x, const float* __restrict__ emb,
                         u16* __restrict__ xe16) {
  int id = blockIdx.x * 256 + threadIdx.x;   // over 32768*128 float4-groups
  int row = id >> 7;                          // b*T + t
  int c = (id & 127) << 2;
  int v = x[row];
  int b = row >> 8;                           // T_ = 256
  int t = row & 255;
  const float4 f = *(const float4*)&emb[(size_t)v * E_ + c];
  ushort4 o;
  o.x = f2bf(f.x); o.y = f2bf(f.y); o.z = f2bf(f.z); o.w = f2bf(f.w);
  *(ushort4*)&xe16[((size_t)(t * B_ + b)) * E_ + c] = o;
}

// ---------------------------------------------------------------- topic bias
__global__ void topicb(const float* __restrict__ x_top, const float* __restrict__ w_th,
                       const float* __restrict__ bias, float* __restrict__ tb) {
  int m = blockIdx.x;
  __shared__ float xt[128];
  if (threadIdx.x < 128) xt[threadIdx.x] = x_top[m * 128 + threadIdx.x];
  __syncthreads();
  for (int g = threadIdx.x; g < G4_; g += 256) {
    const float* wr = &w_th[(size_t)g * 128];
    float s = bias[g];
#pragma unroll 8
    for (int k = 0; k < 128; ++k) s += xt[k] * wr[k];
    tb[(size_t)m * G4_ + g] = s;
  }
}

// ---------------------------------------------------------------- grid barrier
// release on arrive; relaxed spin; single acquire on exit (no per-poll inv)
__device__ __forceinline__ void gridbar(unsigned* cnt, unsigned target) {
  __syncthreads();   // drains vmcnt/lgkm for all waves of the block
  if (threadIdx.x == 0) {
    __hip_atomic_fetch_add(cnt, 1u, __ATOMIC_RELEASE, __HIP_MEMORY_SCOPE_AGENT);
    while (__hip_atomic_load(cnt, __ATOMIC_RELAXED, __HIP_MEMORY_SCOPE_AGENT) < target)
      __builtin_amdgcn_s_sleep(1);
    (void)__hip_atomic_load(cnt, __ATOMIC_ACQUIRE, __HIP_MEMORY_SCOPE_AGENT);
  }
  __syncthreads();
}

// ---------------------------------------------------------------- persistent LSTM
// 128 blocks x 512 threads (8 waves, 2/SIMD). Block j owns h-cols [8j,8j+8)
// (32 gate rows in LDS, XOR-swizzled, 96 KB). Wave w owns m-rows [16w,16w+16).
// A-operands (xe_t | hx) DMA-staged per-wave into private LDS chunks (K=64,
// 3-deep, counted vmcnt) -> barrier-free K-loop. cx and tb in registers.
__global__ __launch_bounds__(512) void lstm_persist(
    const u16* __restrict__ xe, u16* __restrict__ h0, u16* __restrict__ h1,
    const float* __restrict__ wih, const float* __restrict__ whh,
    const float* __restrict__ tb, unsigned* __restrict__ cnt) {
  __shared__ __align__(16) u16 Wl[32 * 1536];     //  98304 B, swizzled slots
  __shared__ __align__(16) u16 Ast[8 * 3 * 1024]; //  49152 B, per-wave 3-buf
  const int j = blockIdx.x;
  const int tid = threadIdx.x;

  // ---- stage weight slice to LDS (fp32->bf16), rows [i(8) f(8) g(8) o(8)],
  //      slot s of row lc stored at (s ^ (lc&7))  (involution)
  for (int idx = tid; idx < 32 * 192; idx += 512) {
    int lc = idx / 192;
    int sg = idx - lc * 192;          // 8-elem slot index 0..191
    int g = (lc >> 3) * H_ + j * 8 + (lc & 7);
    int k0 = sg * 8;
    float4 f0, f1;
    if (k0 < E_) {
      f0 = *(const float4*)&wih[(size_t)g * E_ + k0];
      f1 = *(const float4*)&wih[(size_t)g * E_ + k0 + 4];
    } else {
      f0 = *(const float4*)&whh[(size_t)g * H_ + (k0 - E_)];
      f1 = *(const float4*)&whh[(size_t)g * H_ + (k0 - E_) + 4];
    }
    ushort4 o0, o1;
    o0.x = f2bf(f0.x); o0.y = f2bf(f0.y); o0.z = f2bf(f0.z); o0.w = f2bf(f0.w);
    o1.x = f2bf(f1.x); o1.y = f2bf(f1.y); o1.z = f2bf(f1.z); o1.w = f2bf(f1.w);
    int dst = lc * 1536 + ((sg ^ (lc & 7)) << 3);
    *(ushort4*)&Wl[dst] = o0;
    *(ushort4*)&Wl[dst + 4] = o1;
  }
  __syncthreads();

  const int w = tid >> 6, l = tid & 63, r = l & 15, q = l >> 4;
  const int g0 = (r >> 3) * H_ + j * 8 + (r & 7);   // gate col (i/f)
  const int g1 = g0 + 2 * H_;                        // gate col (g/o)
  const int hcg = j * 8 + (r & 7);
  const bool lower = (r & 8) == 0;
  const int axor = r & 7;
  const int lr0 = l >> 3;          // staging: row within 8-row group
  const int s8 = l & 7;            // staging: slot within row
  u16* const awbase = &Ast[w * 3072];
  const int aoff = r * 64;

  // ---- time-invariant bias into registers
  float tbr0[4], tbr1[4];
#pragma unroll
  for (int rr = 0; rr < 4; ++rr) {
    int m_ = 16 * w + q * 4 + rr;
    tbr0[rr] = tb[(size_t)m_ * G4_ + g0];
    tbr1[rr] = tb[(size_t)m_ * G4_ + g1];
  }
  float cxr[4] = {};

  for (int t = 0; t < T_; ++t) {
    const u16* hin  = (t & 1) ? h1 : h0;
    u16*       hout = (t & 1) ? h0 : h1;

    // stage chunk c (K=64 elems, 16 rows) into buf; source pre-swizzled so
    // linear DMA write + swizzled read = involution (rule #21)
    auto stage = [&](int c, int buf) {
#pragma unroll
      for (int u = 0; u < 2; ++u) {
        int lr = u * 8 + lr0;
        int ks = (s8 ^ (lr & 7)) << 3;
        const u16* g;
        if (c < 8) g = xe + ((size_t)(t * B_ + 16 * w + lr)) * E_ + (c << 6) + ks;
        else       g = hin + ((size_t)(16 * w + lr)) * H_ + ((c - 8) << 6) + ks;
        glds16(g, awbase + buf * 1024 + u * 512);
      }
    };

    stage(0, 0); stage(1, 1); stage(2, 2);   // prologue: xe chunks
    f32x4 acc0 = {}, acc1 = {};
    int buf = 0;
    for (int c = 0; c < 24; ++c) {
      asm volatile("s_waitcnt vmcnt(4)" ::: "memory");  // chunk c landed
      const u16* ab = awbase + buf * 1024;
      bf16x8 a0 = *(const bf16x8*)&ab[aoff + ((q ^ axor) << 3)];
      bf16x8 a1 = *(const bf16x8*)&ab[aoff + (((4 + q) ^ axor) << 3)];
      int sb = c << 3;
      bf16x8 b00 = *(const bf16x8*)&Wl[r * 1536 + (((sb + q) ^ axor) << 3)];
      bf16x8 b01 = *(const bf16x8*)&Wl[(16 + r) * 1536 + (((sb + q) ^ axor) << 3)];
      bf16x8 b10 = *(const bf16x8*)&Wl[r * 1536 + (((sb + 4 + q) ^ axor) << 3)];
      bf16x8 b11 = *(const bf16x8*)&Wl[(16 + r) * 1536 + (((sb + 4 + q) ^ axor) << 3)];
      acc0 = __builtin_amdgcn_mfma_f32_16x16x32_bf16(a0, b00, acc0, 0, 0, 0);
      acc1 = __builtin_amdgcn_mfma_f32_16x16x32_bf16(a0, b01, acc1, 0, 0, 0);
      acc0 = __builtin_amdgcn_mfma_f32_16x16x32_bf16(a1, b10, acc0, 0, 0, 0);
      acc1 = __builtin_amdgcn_mfma_f32_16x16x32_bf16(a1, b11, acc1, 0, 0, 0);
      __builtin_amdgcn_sched_barrier(0);   // keep stage AFTER lgkm-consumed reads
      if (c < 21) stage(c + 3, buf);       // same buf: safe, reads already in regs
      buf = (buf == 2) ? 0 : buf + 1;
    }

    // epilogue: D col = lane&15 (gate col), row = q*4+rr; pair i/f,g/o via xor8
#pragma unroll
    for (int rr = 0; rr < 4; ++rr) {
      float v0 = acc0[rr] + tbr0[rr];
      float v1 = acc1[rr] + tbr1[rr];
      float p0 = __shfl_xor(v0, 8);
      float p1 = __shfl_xor(v1, 8);
      float iv = lower ? v0 : p0;
      float fv = lower ? p0 : v0;
      float gv = lower ? v1 : p1;
      float ov = lower ? p1 : v1;
      iv = fsigmoid(iv);
      fv = fsigmoid(fv);
      ov = fsigmoid(ov);
      gv = ftanh(gv);
      float cn = fv * cxr[rr] + iv * gv;
      cxr[rr] = cn;
      float hn = ov * ftanh(cn);
      if (lower) hout[(size_t)(16 * w + q * 4 + rr) * H_ + hcg] = f2bf(hn);
    }
    gridbar(cnt, (unsigned)(t + 1) * NBLK);
  }
}

// ---------------------------------------------------------------- fc1 + BN
__global__ void fc1_bn(const u16* __restrict__ hxf, const float* __restrict__ w,
                       const float* __restrict__ bvec, const float* __restrict__ gamma,
                       const float* __restrict__ beta, float* __restrict__ h1n) {
  const int f = blockIdx.x;
  const int m = threadIdx.x;
  __shared__ float wrow[H_];
  __shared__ float red[128];
  for (int k = m; k < H_; k += 128) wrow[k] = w[(size_t)f * H_ + k];
  __syncthreads();
  float s = bvec[f];
  const u16* hr = &hxf[(size_t)m * H_];
  for (int k = 0; k < H_; k += 4) {
    ushort4 h4 = *(const ushort4*)&hr[k];
    s += bf2f(h4.x) * wrow[k] + bf2f(h4.y) * wrow[k + 1] +
         bf2f(h4.z) * wrow[k + 2] + bf2f(h4.w) * wrow[k + 3];
  }
  red[m] = s;
  __syncthreads();
  for (int off = 64; off > 0; off >>= 1) {
    if (m < off) red[m] += red[m + off];
    __syncthreads();
  }
  float mu = red[0] * (1.f / 128.f);
  __syncthreads();
  float d = s - mu;
  red[m] = d * d;
  __syncthreads();
  for (int off = 64; off > 0; off >>= 1) {
    if (m < off) red[m] += red[m + off];
    __syncthreads();
  }
  float var = red[0] * (1.f / 128.f);
  h1n[(size_t)m * F_ + f] = d * rsqrtf(var + 1e-5f) * gamma[f] + beta[f];
}

// ---------------------------------------------------------------- fc2
__global__ void fc2k(const float* __restrict__ h1n, const float* __restrict__ w,
                     const float* __restrict__ bvec, float* __restrict__ out) {
  int id = blockIdx.x * 256 + threadIdx.x;   // 1280 total
  if (id >= B_ * O_) return;
  int m = id / O_;
  int o = id - m * O_;
  float s = bvec[o];
  const float* hr = &h1n[(size_t)m * F_];
  const float* wr = &w[(size_t)o * F_];
#pragma unroll 8
  for (int k = 0; k < F_; ++k) s += hr[k] * wr[k];
  out[(size_t)m * O_ + o] = s;
}

// ---------------------------------------------------------------- launch
extern "C" void kernel_launch(void* const* d_in, const int* in_sizes, int n_in,
                              void* d_out, int out_size, void* d_ws, size_t ws_size,
                              hipStream_t stream) {
  const int*   x     = (const int*)  d_in[0];
  const float* x_top = (const float*)d_in[1];
  const float* emb   = (const float*)d_in[2];
  const float* w_ih  = (const float*)d_in[3];
  const float* w_hh  = (const float*)d_in[4];
  const float* w_th  = (const float*)d_in[5];
  const float* bvec  = (const float*)d_in[6];
  const float* fc1_w = (const float*)d_in[7];
  const float* fc1_b = (const float*)d_in[8];
  const float* gamma = (const float*)d_in[9];
  const float* beta  = (const float*)d_in[10];
  const float* fc2_w = (const float*)d_in[11];
  const float* fc2_b = (const float*)d_in[12];
  float* out = (float*)d_out;

  // ws layout (bytes)
  const size_t OFF_XE  = 0;           // 33,554,432  xe16 [T][B][E] bf16
  const size_t OFF_TB  = 33554432;    //  2,097,152  tb   [B][4H] f32
  const size_t OFF_HX0 = 35651584;    //    262,144  hx ping bf16
  const size_t OFF_HX1 = 35913728;    //    262,144  hx pong bf16
  const size_t OFF_CNT = 36175872;    //      4,096  barrier counter
  const size_t OFF_H1  = 36179968;    //    262,144  h1n [B][F] f32
  const size_t NEED    = 36442112;
  if (!d_ws || ws_size < NEED) return;

  char* ws = (char*)d_ws;
  u16*      xe16 = (u16*)(ws + OFF_XE);
  float*    tb   = (float*)(ws + OFF_TB);
  u16*      hx0  = (u16*)(ws + OFF_HX0);
  u16*      hx1  = (u16*)(ws + OFF_HX1);
  unsigned* cnt  = (unsigned*)(ws + OFF_CNT);
  float*    h1n  = (float*)(ws + OFF_H1);

  // zero hx0, hx1, barrier counter (contiguous)
  hipMemsetAsync(ws + OFF_HX0, 0, 262144 * 2 + 4096, stream);

  build_xe<<<16384, 256, 0, stream>>>(x, emb, xe16);
  topicb<<<128, 256, 0, stream>>>(x_top, w_th, bvec, tb);

  {
    const u16* a0 = xe16;
    u16* a1 = hx0; u16* a2 = hx1;
    const float* a3 = w_ih; const float* a4 = w_hh; const float* a5 = tb;
    unsigned* a6 = cnt;
    void* args[] = { (void*)&a0, (void*)&a1, (void*)&a2, (void*)&a3,
                     (void*)&a4, (void*)&a5, (void*)&a6 };
    hipError_t e = hipLaunchCooperativeKernel((void*)lstm_persist, dim3(NBLK),
                                              dim3(512), args, 0, stream);
    if (e != hipSuccess) {
      // fallback: plain launch (128 blocks, 1/CU -> co-resident)
      lstm_persist<<<NBLK, 512, 0, stream>>>(xe16, hx0, hx1, w_ih, w_hh, tb, cnt);
    }
  }
  // T_=256 even -> final hx in hx0

  fc1_bn<<<F_, 128, 0, stream>>>(hx0, fc1_w, fc1_b, gamma, beta, h1n);
  fc2k<<<5, 256, 0, stream>>>(h1n, fc2_w, fc2_b, out);
}